// Round 7
// baseline (376.745 us; speedup 1.0000x reference)
//
#include <hip/hip_runtime.h>
#include <cstdint>
#include <cstddef>

constexpr int N = 50000;      // nodes
constexpr int D = 256;        // D_IN == D_OUT
constexpr int E = 400000;     // edges per relation
constexpr int R = 4;          // relations
constexpr int N4 = N * R;     // (relation,node) pairs
constexpr int AROWS = 50048;  // 391 * 128, padded M
constexpr int ACOLS = 1024;   // 4 msg planes (loop plane lives in xh)
constexpr int KCAT = 1280;    // GEMM K = 4 msg planes + loop plane
constexpr int MAXOVF = 16384;

typedef _Float16 f16x8 __attribute__((ext_vector_type(8)));
typedef _Float16 f16x4 __attribute__((ext_vector_type(4)));
typedef float f32x4 __attribute__((ext_vector_type(4)));

// ---------------------------------------------------------------------------
// Stacked transposed weights: WT[c][k], c in [0,256), k in [0,1280):
//   k < 1024 -> W_{k/256}[k%256][c], else loop_weight[k-1024][c]. fp16.
// ---------------------------------------------------------------------------
__global__ __launch_bounds__(256)
void wt_build_kernel(const float* __restrict__ w, const float* __restrict__ lw,
                     _Float16* __restrict__ wt) {
    const int i = blockIdx.x * blockDim.x + threadIdx.x;  // c*1280 + k
    if (i >= 256 * KCAT) return;
    const int c = i / KCAT;
    const int k = i - c * KCAT;
    const float v = (k < 1024) ? w[((k >> 8) << 16) + ((k & 255) << 8) + c]
                               : lw[((k - 1024) << 8) + c];
    wt[i] = (_Float16)v;
}

// ---------------------------------------------------------------------------
// x fp32 -> compact fp16 plane xh[N][256]
// ---------------------------------------------------------------------------
__global__ __launch_bounds__(256)
void convert_x_kernel(const float* __restrict__ x, _Float16* __restrict__ xh) {
    const long i = (long)blockIdx.x * blockDim.x + threadIdx.x;  // per 8 elems
    if (i >= (long)N * (D / 8)) return;
    const long n = i >> 5;
    const int c8 = (int)(i & 31) << 3;
    const float4* s = reinterpret_cast<const float4*>(x + n * D + c8);
    const float4 a = s[0], b = s[1];
    f16x8 v;
    v[0] = (_Float16)a.x; v[1] = (_Float16)a.y;
    v[2] = (_Float16)a.z; v[3] = (_Float16)a.w;
    v[4] = (_Float16)b.x; v[5] = (_Float16)b.y;
    v[6] = (_Float16)b.z; v[7] = (_Float16)b.w;
    *reinterpret_cast<f16x8*>(xh + n * D + c8) = v;
}

// ---------------------------------------------------------------------------
// Single-pass padded-bucket adjacency build (no scan, no fill pass):
//   p = atomicAdd(cnt[w]); p < maxdeg -> slots[w*maxdeg+p] = src
//   else spill to overflow list (statistically never at maxdeg=64, deg~Poi(8);
//   handled correctly regardless).
// ---------------------------------------------------------------------------
__global__ __launch_bounds__(256)
void build_kernel(const int* __restrict__ edges, int* __restrict__ cnt,
                  ushort* __restrict__ slots, int maxdeg,
                  int2* __restrict__ ovf, int* __restrict__ ovf_n) {
    const int r = blockIdx.y;
    const int* srcp = edges + r * 2 * E;
    const int* dstp = srcp + E;
    int i = blockIdx.x * blockDim.x + threadIdx.x;
    const int stride = gridDim.x * blockDim.x;
    for (; i < E; i += stride) {
        const int s = srcp[i];
        const int w = r * N + dstp[i];
        const int p = atomicAdd(&cnt[w], 1);
        if (p < maxdeg) {
            slots[(long)w * maxdeg + p] = (ushort)s;
        } else {
            const int o = atomicAdd(ovf_n, 1);
            if (o < MAXOVF) ovf[o] = make_int2(w, s);
        }
    }
}

// ---------------------------------------------------------------------------
// Gather: wave per (relation,node) pair w = r*N+n. Lanes 0-31 read even
// edges, 32-63 odd edges, f16x8 (16B/lane) row reads; halves combined via
// one shfl_xor(32). msg = sum * 1/max(deg,1) -> fp16 into A[n][r*256+...].
// ---------------------------------------------------------------------------
__global__ __launch_bounds__(256)
void gather_kernel(const _Float16* __restrict__ xh, const int* __restrict__ cnt,
                   const ushort* __restrict__ slots, int maxdeg,
                   const int2* __restrict__ ovf, const int* __restrict__ ovf_n,
                   _Float16* __restrict__ A) {
    const int w = (blockIdx.x * blockDim.x + threadIdx.x) >> 6;
    const int lane = threadIdx.x & 63;
    if (w >= N4) return;
    const int deg = cnt[w];
    const int m = (deg < maxdeg) ? deg : maxdeg;
    const ushort* sl = slots + (long)w * maxdeg;
    const int half = lane >> 5;
    const int lo8 = (lane & 31) * 8;

    float acc[8] = {};
    for (int j = half; j < m; j += 2) {
        const int s0 = sl[j];
        const f16x8 v = *reinterpret_cast<const f16x8*>(xh + (long)s0 * D + lo8);
#pragma unroll
        for (int k = 0; k < 8; ++k) acc[k] += (float)v[k];
    }
    if (deg > maxdeg) {  // correctness path; statistically never taken
        const int on = min(*ovf_n, MAXOVF);
        for (int o = 0; o < on; ++o) {
            const int2 e = ovf[o];
            if (e.x == w && half == 0) {  // count once (halves are summed below)
                const f16x8 v =
                    *reinterpret_cast<const f16x8*>(xh + (long)e.y * D + lo8);
#pragma unroll
                for (int k = 0; k < 8; ++k) acc[k] += (float)v[k];
            }
        }
    }
#pragma unroll
    for (int k = 0; k < 8; ++k) acc[k] += __shfl_xor(acc[k], 32);

    if (half == 0) {
        const float rs = 1.0f / fmaxf((float)deg, 1.0f);
        f16x8 o;
#pragma unroll
        for (int k = 0; k < 8; ++k) o[k] = (_Float16)(acc[k] * rs);
        const int r = w / N;
        const int n = w - r * N;
        *reinterpret_cast<f16x8*>(A + (long)n * ACOLS + r * 256 + lo8) = o;
    }
}

// ---------------------------------------------------------------------------
// out[N,256] = tanh( [A | xh] @ WT^T + bias ), fp32 accum/out.
// BM=128, BN=128, BK=32, 4 waves (2x2), grid (AROWS/128, 2) = 782 blocks.
// k-subtiled LDS [4][128][8] (conflict-free ds_read_b128).
// A rows >= N hold garbage: harmless (MFMA row-independence + guarded store).
// ---------------------------------------------------------------------------
__global__ __launch_bounds__(256)
void gemm_final_kernel(const _Float16* __restrict__ A,
                       const _Float16* __restrict__ xh,
                       const _Float16* __restrict__ WT,
                       const float* __restrict__ bias, float* __restrict__ C) {
    __shared__ _Float16 As[4][128][8];
    __shared__ _Float16 Bs[4][128][8];

    const int t = threadIdx.x;
    const int lane = t & 63;
    const int w = t >> 6;
    const int wr = w >> 1;
    const int wc = w & 1;
    const long m0 = (long)blockIdx.x * 128;
    const int n0 = blockIdx.y * 128;

    const int srow = t >> 1;   // stage row 0..127
    const int half = t & 1;    // which 16-wide k half
    const int skg = half * 2;
    const long arow = m0 + srow;
    const _Float16* Bg = WT + (long)(n0 + srow) * KCAT + half * 16;

    f32x4 acc[4][4];
#pragma unroll
    for (int i = 0; i < 4; ++i)
#pragma unroll
        for (int j = 0; j < 4; ++j) acc[i][j] = (f32x4){0.f, 0.f, 0.f, 0.f};

    const int kg = lane >> 4;
    const int rr = lane & 15;

    for (int k0 = 0; k0 < KCAT; k0 += 32) {
        const _Float16* Ap = (k0 < ACOLS)
                                 ? A + arow * ACOLS + k0 + half * 16
                                 : xh + arow * D + (k0 - ACOLS) + half * 16;
        const uint4 av0 = *reinterpret_cast<const uint4*>(Ap);
        const uint4 av1 = *reinterpret_cast<const uint4*>(Ap + 8);
        const uint4 bv0 = *reinterpret_cast<const uint4*>(Bg + k0);
        const uint4 bv1 = *reinterpret_cast<const uint4*>(Bg + k0 + 8);
        __syncthreads();  // previous iteration's frag reads done
        *reinterpret_cast<uint4*>(&As[skg + 0][srow][0]) = av0;
        *reinterpret_cast<uint4*>(&As[skg + 1][srow][0]) = av1;
        *reinterpret_cast<uint4*>(&Bs[skg + 0][srow][0]) = bv0;
        *reinterpret_cast<uint4*>(&Bs[skg + 1][srow][0]) = bv1;
        __syncthreads();

        f16x8 af[4], bf[4];
#pragma unroll
        for (int f = 0; f < 4; ++f) {
            af[f] = *reinterpret_cast<const f16x8*>(&As[kg][wr * 64 + f * 16 + rr][0]);
            bf[f] = *reinterpret_cast<const f16x8*>(&Bs[kg][wc * 64 + f * 16 + rr][0]);
        }
#pragma unroll
        for (int i = 0; i < 4; ++i)
#pragma unroll
            for (int j = 0; j < 4; ++j)
                acc[i][j] = __builtin_amdgcn_mfma_f32_16x16x32_f16(
                    af[i], bf[j], acc[i][j], 0, 0, 0);
    }

    // epilogue: C/D map col=lane&15, row=(lane>>4)*4+reg
    const int crow0 = (lane >> 4) * 4;
    const int ccol = lane & 15;
#pragma unroll
    for (int i = 0; i < 4; ++i) {
        const long row = m0 + wr * 64 + i * 16 + crow0;
#pragma unroll
        for (int j = 0; j < 4; ++j) {
            const int col = n0 + wc * 64 + j * 16 + ccol;
            const float b = bias[col];
#pragma unroll
            for (int q = 0; q < 4; ++q) {
                const long rgl = row + q;
                if (rgl < N) C[rgl * 256 + col] = tanhf(acc[i][j][q] + b);
            }
        }
    }
}

// ---------------------------------------------------------------------------
extern "C" void kernel_launch(void* const* d_in, const int* in_sizes, int n_in,
                              void* d_out, int out_size, void* d_ws, size_t ws_size,
                              hipStream_t stream) {
    const float* x           = (const float*)d_in[0];
    const int*   edges       = (const int*)d_in[1];   // [4][2][400000] int32
    const float* weight      = (const float*)d_in[2]; // [4][256][256]
    const float* loop_weight = (const float*)d_in[3]; // [256][256]
    const float* h_bias      = (const float*)d_in[4]; // [256]
    float*       out         = (float*)d_out;
    (void)in_sizes; (void)n_in; (void)out_size;

    size_t off = 0;
    auto carve = [&](size_t bytes) -> void* {
        void* p = (char*)d_ws + off;
        off = (off + bytes + 255) & ~(size_t)255;
        return p;
    };

    const size_t a_bytes  = (size_t)AROWS * ACOLS * sizeof(_Float16);  // 102.5 MB
    const size_t xh_bytes = (size_t)N * D * sizeof(_Float16);          // 25.6 MB
    const size_t fixed    = (size_t)KCAT * 256 * sizeof(_Float16)      // WT
                          + (size_t)N4 * sizeof(int)                   // cnt
                          + MAXOVF * sizeof(int2) + 4096;
    // maxdeg=64 needs ~155 MB; 32 as fallback (still P(overflow) ~ 1e-9/node).
    const int maxdeg =
        (ws_size >= a_bytes + xh_bytes + (size_t)N4 * 64 * sizeof(ushort) + fixed)
            ? 64 : 32;

    _Float16* A     = (_Float16*)carve(a_bytes);
    _Float16* xh    = (_Float16*)carve(xh_bytes);
    ushort*   slots = (ushort*)carve((size_t)N4 * maxdeg * sizeof(ushort));
    _Float16* WT    = (_Float16*)carve((size_t)KCAT * 256 * sizeof(_Float16));
    int*      cnt   = (int*)carve((size_t)N4 * sizeof(int));
    int*      ovf_n = (int*)carve(256);
    int2*     ovf   = (int2*)carve(MAXOVF * sizeof(int2));

    hipMemsetAsync(cnt, 0, (size_t)N4 * sizeof(int), stream);
    hipMemsetAsync(ovf_n, 0, sizeof(int), stream);

    wt_build_kernel<<<(256 * KCAT + 255) / 256, 256, 0, stream>>>(weight, loop_weight, WT);
    convert_x_kernel<<<(N * (D / 8) + 255) / 256, 256, 0, stream>>>(x, xh);

    // single-pass adjacency build
    build_kernel<<<dim3(512, R), 256, 0, stream>>>(edges, cnt, slots, maxdeg, ovf, ovf_n);

    // msg planes into A columns [0,1024)
    gather_kernel<<<(N4 * 64) / 256, 256, 0, stream>>>(xh, cnt, slots, maxdeg,
                                                       ovf, ovf_n, A);

    // out = tanh([A | xh] @ Wcat + bias)
    gemm_final_kernel<<<dim3(AROWS / 128, 2), 256, 0, stream>>>(A, xh, WT, h_bias, out);
}

// Round 8
// 288.964 us; speedup vs baseline: 1.3038x; 1.3038x over previous
//
#include <hip/hip_runtime.h>
#include <cstdint>
#include <cstddef>

constexpr int N = 50000;      // nodes
constexpr int D = 256;        // D_IN == D_OUT
constexpr int E = 400000;     // edges per relation
constexpr int R = 4;          // relations
constexpr int N4 = N * R;
constexpr int AROWS = 50048;  // 391 * 128, padded M
constexpr int ACOLS = 1024;   // 4 msg planes (loop plane lives in xh)
constexpr int KCAT = 1280;    // GEMM K = 4 msg planes + loop plane

constexpr int NBPR = 196;     // dst buckets per relation (ceil(N/256))
constexpr int NBKT = NBPR * R;        // 784
constexpr int BCAP = 2560;            // records per bucket (mean 2048, +11 sigma)
constexpr int MAXDEG = 32;            // LDS slots per node (P(Poi(8)>32) ~ 3e-12)
constexpr int ECHUNK = 4096;          // edges per partition block
constexpr int NCHUNKS = (E + ECHUNK - 1) / ECHUNK;  // 98
constexpr int MAXOVF = 4096;          // bucket-cap overflow list (never in practice)

typedef _Float16 f16x8 __attribute__((ext_vector_type(8)));
typedef float f32x4 __attribute__((ext_vector_type(4)));

__device__ __forceinline__ void load_lds16(const void* g, void* l) {
    __builtin_amdgcn_global_load_lds(
        (const __attribute__((address_space(1))) void*)g,
        (__attribute__((address_space(3))) void*)l, 16, 0, 0);
}

// ---------------------------------------------------------------------------
// Stacked transposed weights: WT[c][k], k<1024 -> W_{k/256}[k%256][c],
// else loop_weight[k-1024][c]. fp16.
// ---------------------------------------------------------------------------
__global__ __launch_bounds__(256)
void wt_build_kernel(const float* __restrict__ w, const float* __restrict__ lw,
                     _Float16* __restrict__ wt) {
    const int i = blockIdx.x * blockDim.x + threadIdx.x;  // c*1280 + k
    if (i >= 256 * KCAT) return;
    const int c = i / KCAT;
    const int k = i - c * KCAT;
    const float v = (k < 1024) ? w[((k >> 8) << 16) + ((k & 255) << 8) + c]
                               : lw[((k - 1024) << 8) + c];
    wt[i] = (_Float16)v;
}

// ---------------------------------------------------------------------------
// x fp32 -> compact fp16 plane xh[N][256]
// ---------------------------------------------------------------------------
__global__ __launch_bounds__(256)
void convert_x_kernel(const float* __restrict__ x, _Float16* __restrict__ xh) {
    const long i = (long)blockIdx.x * blockDim.x + threadIdx.x;  // per 8 elems
    if (i >= (long)N * (D / 8)) return;
    const long n = i >> 5;
    const int c8 = (int)(i & 31) << 3;
    const float4* s = reinterpret_cast<const float4*>(x + n * D + c8);
    const float4 a = s[0], b = s[1];
    f16x8 v;
    v[0] = (_Float16)a.x; v[1] = (_Float16)a.y;
    v[2] = (_Float16)a.z; v[3] = (_Float16)a.w;
    v[4] = (_Float16)b.x; v[5] = (_Float16)b.y;
    v[6] = (_Float16)b.z; v[7] = (_Float16)b.w;
    *reinterpret_cast<f16x8*>(xh + n * D + c8) = v;
}

// ---------------------------------------------------------------------------
// Pass A: multisplit edges into 196 dst-range buckets per relation.
// Per block: LDS histogram -> LDS scan -> staged (bucket-sorted) records ->
// one global atomic per (block,bucket) to reserve a run -> coalesced write.
// Record = (src16 << 16) | dst16.
// ---------------------------------------------------------------------------
__global__ __launch_bounds__(256)
void partition_kernel(const int* __restrict__ edges, int* __restrict__ gcnt,
                      uint* __restrict__ buckets, int* __restrict__ ovf_n,
                      int2* __restrict__ ovf) {
    __shared__ int hist[256], base[256], run[256], gbase[256], ps[256];
    __shared__ int tot_s;
    __shared__ uint staging[ECHUNK];
    const int t = threadIdx.x;
    const int r = blockIdx.y;
    const int* srcp = edges + (size_t)r * 2 * E;
    const int* dstp = srcp + E;
    const int e0 = blockIdx.x * ECHUNK;

    hist[t] = 0;
    run[t] = 0;
    __syncthreads();

    uint rec[16];
#pragma unroll
    for (int u = 0; u < 16; ++u) {
        const int i = e0 + u * 256 + t;
        if (i < E) {
            rec[u] = ((uint)srcp[i] << 16) | (uint)dstp[i];
            atomicAdd(&hist[(rec[u] & 0xFFFFu) >> 8], 1);
        } else {
            rec[u] = 0xFFFFFFFFu;  // invalid marker (src=65535 impossible)
        }
    }
    __syncthreads();

    // exclusive scan of hist (256 bins, Hillis-Steele)
    const int v = hist[t];
    ps[t] = v;
    __syncthreads();
    for (int off = 1; off < 256; off <<= 1) {
        const int x = (t >= off) ? ps[t - off] : 0;
        __syncthreads();
        ps[t] += x;
        __syncthreads();
    }
    base[t] = ps[t] - v;
    if (t == 255) tot_s = ps[255];
    if (v > 0) gbase[t] = atomicAdd(&gcnt[r * NBPR + t], v);
    __syncthreads();

    // place records bucket-sorted into LDS staging
#pragma unroll
    for (int u = 0; u < 16; ++u) {
        if (rec[u] != 0xFFFFFFFFu) {
            const int bl = (rec[u] & 0xFFFFu) >> 8;
            const int pos = base[bl] + atomicAdd(&run[bl], 1);
            staging[pos] = rec[u];
        }
    }
    __syncthreads();

    // coalesced write-out of per-bucket runs
    const int total = tot_s;
    for (int j = t; j < total; j += 256) {
        const uint rc = staging[j];
        const int bl = (rc & 0xFFFFu) >> 8;
        const int gp = gbase[bl] + (j - base[bl]);
        if (gp < BCAP) {
            buckets[(size_t)(r * NBPR + bl) * BCAP + gp] = rc;
        } else {  // statistically never (11 sigma); correctness fallback
            const int o = atomicAdd(ovf_n, 1);
            if (o < MAXOVF)
                ovf[o] = make_int2(r * N + (int)(rc & 0xFFFFu), (int)(rc >> 16));
        }
    }
}

// ---------------------------------------------------------------------------
// Pass B fused with gather: one block per (bucket, quarter) = 64 dst nodes.
// Build per-node slot lists in LDS (LDS atomics only), then gather xh rows,
// normalize by true degree, write fp16 msg rows into A. No global CSR.
// ---------------------------------------------------------------------------
__global__ __launch_bounds__(256)
void bucket_gather_kernel(const uint* __restrict__ buckets,
                          const int* __restrict__ gcnt,
                          const _Float16* __restrict__ xh,
                          const int2* __restrict__ ovf,
                          const int* __restrict__ ovf_n,
                          _Float16* __restrict__ A) {
    __shared__ int lcnt[64];
    __shared__ ushort lslots[64][MAXDEG];
    const int t = threadIdx.x;
    const int b = blockIdx.x >> 2;       // bucket 0..783
    const int quarter = blockIdx.x & 3;  // 64-node quarter
    const int r = b / NBPR;
    const int bl = b - r * NBPR;
    const int d0 = (bl << 8) + (quarter << 6);

    if (t < 64) lcnt[t] = 0;
    __syncthreads();

    const int nb = min(gcnt[b], BCAP);
    const uint* brec = buckets + (size_t)b * BCAP;
    for (int j = t; j < nb; j += 256) {
        const uint rc = brec[j];
        const int wi = (int)(rc & 0xFFFFu) - d0;
        if ((unsigned)wi < 64u) {
            const int pos = atomicAdd(&lcnt[wi], 1);
            if (pos < MAXDEG) lslots[wi][pos] = (ushort)(rc >> 16);
            // pos >= MAXDEG: counted in lcnt; rows recovered by direct scan below
        }
    }
    __syncthreads();

    const int lane = t & 63;
    const int wv = t >> 6;           // wave 0..3 handles 16 nodes
    const int hf = lane >> 5;        // half-wave: even/odd edges
    const int lo8 = (lane & 31) * 8;
    const int on = min(*ovf_n, MAXOVF);

    for (int wi = wv * 16; wi < wv * 16 + 16; ++wi) {
        const int d = d0 + wi;
        if (d >= N) continue;
        const int m = lcnt[wi];
        float acc[8] = {};
        if (m <= MAXDEG) {
            for (int j = hf; j < m; j += 2) {
                const int s = lslots[wi][j];
                const f16x8 vv =
                    *reinterpret_cast<const f16x8*>(xh + (size_t)s * D + lo8);
#pragma unroll
                for (int k = 0; k < 8; ++k) acc[k] += (float)vv[k];
            }
        } else {  // slot overflow (never in practice): direct bucket scan
            for (int j = hf; j < nb; j += 2) {
                const uint rc = brec[j];
                if ((int)(rc & 0xFFFFu) == d) {
                    const f16x8 vv = *reinterpret_cast<const f16x8*>(
                        xh + (size_t)(rc >> 16) * D + lo8);
#pragma unroll
                    for (int k = 0; k < 8; ++k) acc[k] += (float)vv[k];
                }
            }
        }
        int ecnt = m;
        if (on > 0) {  // bucket-cap overflow entries (read-only here)
            const int wfull = r * N + d;
            for (int o = 0; o < on; ++o) {
                const int2 e2 = ovf[o];
                if (e2.x == wfull) {
                    ecnt++;
                    if (hf == 0) {
                        const f16x8 vv = *reinterpret_cast<const f16x8*>(
                            xh + (size_t)e2.y * D + lo8);
#pragma unroll
                        for (int k = 0; k < 8; ++k) acc[k] += (float)vv[k];
                    }
                }
            }
        }
#pragma unroll
        for (int k = 0; k < 8; ++k) acc[k] += __shfl_xor(acc[k], 32);
        if (hf == 0) {
            const float rs = 1.0f / fmaxf((float)ecnt, 1.0f);
            f16x8 o8;
#pragma unroll
            for (int k = 0; k < 8; ++k) o8[k] = (_Float16)(acc[k] * rs);
            *reinterpret_cast<f16x8*>(A + (size_t)d * ACOLS + r * 256 + lo8) = o8;
        }
    }
}

// ---------------------------------------------------------------------------
// out[N,256] = tanh( [A | xh] @ WT^T + bias ), fp32 accum/out.
// BM=128, BN=128, BK=32, 4 waves (2x2). Staging via global_load_lds width=16:
// wave w fills k-subtile plane w (cols k0+w*8..+8) of As/Bs; LDS dest is
// wave-uniform base + lane*16B (rows q*64+lane), per-lane global source.
// Frag-read layout [4][128][8] unchanged (conflict-free ds_read_b128).
// A/xh rows >= N hold garbage: harmless (row-independent MFMA, guarded store).
// ---------------------------------------------------------------------------
__global__ __launch_bounds__(256)
void gemm_final_kernel(const _Float16* __restrict__ A,
                       const _Float16* __restrict__ xh,
                       const _Float16* __restrict__ WT,
                       const float* __restrict__ bias, float* __restrict__ C) {
    __shared__ _Float16 As[4][128][8];
    __shared__ _Float16 Bs[4][128][8];

    const int t = threadIdx.x;
    const int lane = t & 63;
    const int w = t >> 6;
    const int wr = w >> 1;
    const int wc = w & 1;
    const long m0 = (long)blockIdx.x * 128;
    const int n0 = blockIdx.y * 128;

    _Float16* asd0 = &As[w][0][0];
    _Float16* asd1 = &As[w][64][0];
    _Float16* bsd0 = &Bs[w][0][0];
    _Float16* bsd1 = &Bs[w][64][0];
    const long ar0 = m0 + lane, ar1 = m0 + 64 + lane;
    const _Float16* Aa0 = A + ar0 * ACOLS + w * 8;
    const _Float16* Aa1 = A + ar1 * ACOLS + w * 8;
    const _Float16* Ax0 = xh + ar0 * D + w * 8;
    const _Float16* Ax1 = xh + ar1 * D + w * 8;
    const _Float16* Bg0 = WT + (long)(n0 + lane) * KCAT + w * 8;
    const _Float16* Bg1 = WT + (long)(n0 + 64 + lane) * KCAT + w * 8;

    f32x4 acc[4][4];
#pragma unroll
    for (int i = 0; i < 4; ++i)
#pragma unroll
        for (int j = 0; j < 4; ++j) acc[i][j] = (f32x4){0.f, 0.f, 0.f, 0.f};

    const int kg = lane >> 4;
    const int rr = lane & 15;

    for (int k0 = 0; k0 < KCAT; k0 += 32) {
        __syncthreads();  // previous iteration's frag reads done
        if (k0 < ACOLS) {
            load_lds16(Aa0 + k0, asd0);
            load_lds16(Aa1 + k0, asd1);
        } else {
            load_lds16(Ax0 + (k0 - ACOLS), asd0);
            load_lds16(Ax1 + (k0 - ACOLS), asd1);
        }
        load_lds16(Bg0 + k0, bsd0);
        load_lds16(Bg1 + k0, bsd1);
        __syncthreads();  // vmcnt(0) drained by all waves -> tile ready

        f16x8 af[4], bf[4];
#pragma unroll
        for (int f = 0; f < 4; ++f) {
            af[f] = *reinterpret_cast<const f16x8*>(&As[kg][wr * 64 + f * 16 + rr][0]);
            bf[f] = *reinterpret_cast<const f16x8*>(&Bs[kg][wc * 64 + f * 16 + rr][0]);
        }
#pragma unroll
        for (int i = 0; i < 4; ++i)
#pragma unroll
            for (int j = 0; j < 4; ++j)
                acc[i][j] = __builtin_amdgcn_mfma_f32_16x16x32_f16(
                    af[i], bf[j], acc[i][j], 0, 0, 0);
    }

    // epilogue: C/D map col=lane&15, row=(lane>>4)*4+reg
    const int crow0 = (lane >> 4) * 4;
    const int ccol = lane & 15;
#pragma unroll
    for (int i = 0; i < 4; ++i) {
        const long row = m0 + wr * 64 + i * 16 + crow0;
#pragma unroll
        for (int j = 0; j < 4; ++j) {
            const int col = n0 + wc * 64 + j * 16 + ccol;
            const float b = bias[col];
#pragma unroll
            for (int q = 0; q < 4; ++q) {
                const long rgl = row + q;
                if (rgl < N) C[rgl * 256 + col] = tanhf(acc[i][j][q] + b);
            }
        }
    }
}

// ---------------------------------------------------------------------------
extern "C" void kernel_launch(void* const* d_in, const int* in_sizes, int n_in,
                              void* d_out, int out_size, void* d_ws, size_t ws_size,
                              hipStream_t stream) {
    const float* x           = (const float*)d_in[0];
    const int*   edges       = (const int*)d_in[1];   // [4][2][400000] int32
    const float* weight      = (const float*)d_in[2]; // [4][256][256]
    const float* loop_weight = (const float*)d_in[3]; // [256][256]
    const float* h_bias      = (const float*)d_in[4]; // [256]
    float*       out         = (float*)d_out;
    (void)in_sizes; (void)n_in; (void)out_size; (void)ws_size;

    size_t off = 0;
    auto carve = [&](size_t bytes) -> void* {
        void* p = (char*)d_ws + off;
        off = (off + bytes + 255) & ~(size_t)255;
        return p;
    };

    _Float16* A     = (_Float16*)carve((size_t)AROWS * ACOLS * sizeof(_Float16));
    _Float16* xh    = (_Float16*)carve((size_t)AROWS * D * sizeof(_Float16));
    _Float16* WT    = (_Float16*)carve((size_t)KCAT * 256 * sizeof(_Float16));
    int*      gcnt  = (int*)carve((size_t)NBKT * sizeof(int));
    int*      ovf_n = (int*)carve(256);
    int2*     ovf   = (int2*)carve((size_t)MAXOVF * sizeof(int2));
    // ws total ~129 MB (r7 proved >= 142.5 MB available).
    // bucket array (8 MB) aliases d_out: dead before gemm_final overwrites it.
    uint* buckets = (uint*)d_out;  // NBKT*BCAP*4 = 8.03 MB <= 51.2 MB

    hipMemsetAsync(gcnt, 0, (size_t)NBKT * sizeof(int), stream);
    hipMemsetAsync(ovf_n, 0, sizeof(int), stream);

    wt_build_kernel<<<(256 * KCAT + 255) / 256, 256, 0, stream>>>(weight, loop_weight, WT);
    convert_x_kernel<<<(N * (D / 8) + 255) / 256, 256, 0, stream>>>(x, xh);

    // multisplit edges -> dst-range buckets
    partition_kernel<<<dim3(NCHUNKS, R), 256, 0, stream>>>(edges, gcnt, buckets,
                                                           ovf_n, ovf);
    // LDS slot build + gather fused; writes msg planes into A
    bucket_gather_kernel<<<NBKT * 4, 256, 0, stream>>>(buckets, gcnt, xh,
                                                       ovf, ovf_n, A);
    // out = tanh([A | xh] @ Wcat + bias)
    gemm_final_kernel<<<dim3(AROWS / 128, 2), 256, 0, stream>>>(A, xh, WT, h_bias, out);
}

// Round 9
// 288.264 us; speedup vs baseline: 1.3069x; 1.0024x over previous
//
#include <hip/hip_runtime.h>
#include <cstdint>
#include <cstddef>

constexpr int N = 50000;      // nodes
constexpr int D = 256;        // D_IN == D_OUT
constexpr int E = 400000;     // edges per relation
constexpr int R = 4;          // relations
constexpr int N4 = N * R;
constexpr int AROWS = 50048;  // 391 * 128, padded M
constexpr int ACOLS = 1024;   // 4 msg planes (loop plane lives in xh)
constexpr int KCAT = 1280;    // GEMM K = 4 msg planes + loop plane

constexpr int NBPR = 196;     // dst buckets per relation (ceil(N/256))
constexpr int NBKT = NBPR * R;        // 784
constexpr int BCAP = 2560;            // records per bucket (mean 2048, +11 sigma)
constexpr int MAXDEG = 32;            // LDS slots per node (P(Poi(8)>32) ~ 3e-12)
constexpr int ECHUNK = 4096;          // edges per partition block
constexpr int NCHUNKS = (E + ECHUNK - 1) / ECHUNK;  // 98
constexpr int MAXOVF = 4096;          // bucket-cap overflow list (never in practice)

typedef _Float16 f16x8 __attribute__((ext_vector_type(8)));
typedef float f32x4 __attribute__((ext_vector_type(4)));

__device__ __forceinline__ void load_lds16(const void* g, void* l) {
    __builtin_amdgcn_global_load_lds(
        (const __attribute__((address_space(1))) void*)g,
        (__attribute__((address_space(3))) void*)l, 16, 0, 0);
}

// ---------------------------------------------------------------------------
// Stacked transposed weights: WT[c][k], k<1024 -> W_{k/256}[k%256][c],
// else loop_weight[k-1024][c]. fp16.
// ---------------------------------------------------------------------------
__global__ __launch_bounds__(256)
void wt_build_kernel(const float* __restrict__ w, const float* __restrict__ lw,
                     _Float16* __restrict__ wt) {
    const int i = blockIdx.x * blockDim.x + threadIdx.x;  // c*1280 + k
    if (i >= 256 * KCAT) return;
    const int c = i / KCAT;
    const int k = i - c * KCAT;
    const float v = (k < 1024) ? w[((k >> 8) << 16) + ((k & 255) << 8) + c]
                               : lw[((k - 1024) << 8) + c];
    wt[i] = (_Float16)v;
}

// ---------------------------------------------------------------------------
// x fp32 -> compact fp16 plane xh[N][256]
// ---------------------------------------------------------------------------
__global__ __launch_bounds__(256)
void convert_x_kernel(const float* __restrict__ x, _Float16* __restrict__ xh) {
    const long i = (long)blockIdx.x * blockDim.x + threadIdx.x;  // per 8 elems
    if (i >= (long)N * (D / 8)) return;
    const long n = i >> 5;
    const int c8 = (int)(i & 31) << 3;
    const float4* s = reinterpret_cast<const float4*>(x + n * D + c8);
    const float4 a = s[0], b = s[1];
    f16x8 v;
    v[0] = (_Float16)a.x; v[1] = (_Float16)a.y;
    v[2] = (_Float16)a.z; v[3] = (_Float16)a.w;
    v[4] = (_Float16)b.x; v[5] = (_Float16)b.y;
    v[6] = (_Float16)b.z; v[7] = (_Float16)b.w;
    *reinterpret_cast<f16x8*>(xh + n * D + c8) = v;
}

// ---------------------------------------------------------------------------
// Pass A: multisplit edges into 196 dst-range buckets per relation.
// Per block: LDS histogram -> LDS scan -> staged (bucket-sorted) records ->
// one global atomic per (block,bucket) to reserve a run -> coalesced write.
// Record = (src16 << 16) | dst16.
// ---------------------------------------------------------------------------
__global__ __launch_bounds__(256)
void partition_kernel(const int* __restrict__ edges, int* __restrict__ gcnt,
                      uint* __restrict__ buckets, int* __restrict__ ovf_n,
                      int2* __restrict__ ovf) {
    __shared__ int hist[256], base[256], run[256], gbase[256], ps[256];
    __shared__ int tot_s;
    __shared__ uint staging[ECHUNK];
    const int t = threadIdx.x;
    const int r = blockIdx.y;
    const int* srcp = edges + (size_t)r * 2 * E;
    const int* dstp = srcp + E;
    const int e0 = blockIdx.x * ECHUNK;

    hist[t] = 0;
    run[t] = 0;
    __syncthreads();

    uint rec[16];
#pragma unroll
    for (int u = 0; u < 16; ++u) {
        const int i = e0 + u * 256 + t;
        if (i < E) {
            rec[u] = ((uint)srcp[i] << 16) | (uint)dstp[i];
            atomicAdd(&hist[(rec[u] & 0xFFFFu) >> 8], 1);
        } else {
            rec[u] = 0xFFFFFFFFu;  // invalid marker (src=65535 impossible)
        }
    }
    __syncthreads();

    // exclusive scan of hist (256 bins, Hillis-Steele)
    const int v = hist[t];
    ps[t] = v;
    __syncthreads();
    for (int off = 1; off < 256; off <<= 1) {
        const int x = (t >= off) ? ps[t - off] : 0;
        __syncthreads();
        ps[t] += x;
        __syncthreads();
    }
    base[t] = ps[t] - v;
    if (t == 255) tot_s = ps[255];
    if (v > 0) gbase[t] = atomicAdd(&gcnt[r * NBPR + t], v);
    __syncthreads();

    // place records bucket-sorted into LDS staging
#pragma unroll
    for (int u = 0; u < 16; ++u) {
        if (rec[u] != 0xFFFFFFFFu) {
            const int bl = (rec[u] & 0xFFFFu) >> 8;
            const int pos = base[bl] + atomicAdd(&run[bl], 1);
            staging[pos] = rec[u];
        }
    }
    __syncthreads();

    // coalesced write-out of per-bucket runs
    const int total = tot_s;
    for (int j = t; j < total; j += 256) {
        const uint rc = staging[j];
        const int bl = (rc & 0xFFFFu) >> 8;
        const int gp = gbase[bl] + (j - base[bl]);
        if (gp < BCAP) {
            buckets[(size_t)(r * NBPR + bl) * BCAP + gp] = rc;
        } else {  // statistically never (11 sigma); correctness fallback
            const int o = atomicAdd(ovf_n, 1);
            if (o < MAXOVF)
                ovf[o] = make_int2(r * N + (int)(rc & 0xFFFFu), (int)(rc >> 16));
        }
    }
}

// ---------------------------------------------------------------------------
// Pass B fused with gather: one block per (bucket, quarter) = 64 dst nodes.
// Build per-node slot lists in LDS (LDS atomics only), then gather xh rows,
// normalize by true degree, write fp16 msg rows into A. No global CSR.
// ---------------------------------------------------------------------------
__global__ __launch_bounds__(256)
void bucket_gather_kernel(const uint* __restrict__ buckets,
                          const int* __restrict__ gcnt,
                          const _Float16* __restrict__ xh,
                          const int2* __restrict__ ovf,
                          const int* __restrict__ ovf_n,
                          _Float16* __restrict__ A) {
    __shared__ int lcnt[64];
    __shared__ ushort lslots[64][MAXDEG];
    const int t = threadIdx.x;
    const int b = blockIdx.x >> 2;       // bucket 0..783
    const int quarter = blockIdx.x & 3;  // 64-node quarter
    const int r = b / NBPR;
    const int bl = b - r * NBPR;
    const int d0 = (bl << 8) + (quarter << 6);

    if (t < 64) lcnt[t] = 0;
    __syncthreads();

    const int nb = min(gcnt[b], BCAP);
    const uint* brec = buckets + (size_t)b * BCAP;
    for (int j = t; j < nb; j += 256) {
        const uint rc = brec[j];
        const int wi = (int)(rc & 0xFFFFu) - d0;
        if ((unsigned)wi < 64u) {
            const int pos = atomicAdd(&lcnt[wi], 1);
            if (pos < MAXDEG) lslots[wi][pos] = (ushort)(rc >> 16);
            // pos >= MAXDEG: counted in lcnt; rows recovered by direct scan below
        }
    }
    __syncthreads();

    const int lane = t & 63;
    const int wv = t >> 6;           // wave 0..3 handles 16 nodes
    const int hf = lane >> 5;        // half-wave: even/odd edges
    const int lo8 = (lane & 31) * 8;
    const int on = min(*ovf_n, MAXOVF);

    for (int wi = wv * 16; wi < wv * 16 + 16; ++wi) {
        const int d = d0 + wi;
        if (d >= N) continue;
        const int m = lcnt[wi];
        float acc[8] = {};
        if (m <= MAXDEG) {
            for (int j = hf; j < m; j += 2) {
                const int s = lslots[wi][j];
                const f16x8 vv =
                    *reinterpret_cast<const f16x8*>(xh + (size_t)s * D + lo8);
#pragma unroll
                for (int k = 0; k < 8; ++k) acc[k] += (float)vv[k];
            }
        } else {  // slot overflow (never in practice): direct bucket scan
            for (int j = hf; j < nb; j += 2) {
                const uint rc = brec[j];
                if ((int)(rc & 0xFFFFu) == d) {
                    const f16x8 vv = *reinterpret_cast<const f16x8*>(
                        xh + (size_t)(rc >> 16) * D + lo8);
#pragma unroll
                    for (int k = 0; k < 8; ++k) acc[k] += (float)vv[k];
                }
            }
        }
        int ecnt = m;
        if (on > 0) {  // bucket-cap overflow entries (read-only here)
            const int wfull = r * N + d;
            for (int o = 0; o < on; ++o) {
                const int2 e2 = ovf[o];
                if (e2.x == wfull) {
                    ecnt++;
                    if (hf == 0) {
                        const f16x8 vv = *reinterpret_cast<const f16x8*>(
                            xh + (size_t)e2.y * D + lo8);
#pragma unroll
                        for (int k = 0; k < 8; ++k) acc[k] += (float)vv[k];
                    }
                }
            }
        }
#pragma unroll
        for (int k = 0; k < 8; ++k) acc[k] += __shfl_xor(acc[k], 32);
        if (hf == 0) {
            const float rs = 1.0f / fmaxf((float)ecnt, 1.0f);
            f16x8 o8;
#pragma unroll
            for (int k = 0; k < 8; ++k) o8[k] = (_Float16)(acc[k] * rs);
            *reinterpret_cast<f16x8*>(A + (size_t)d * ACOLS + r * 256 + lo8) = o8;
        }
    }
}

// ---------------------------------------------------------------------------
// out[N,256] = tanh( [A | xh] @ WT^T + bias ), fp32 accum/out.
// BM=128, BN=128, BK=32, 4 waves (2x2). 2-PHASE double-buffered pipeline:
// issue next tile's global_load_lds BEFORE computing current tile; one
// per-wave `s_waitcnt vmcnt(0)` + one RAW s_barrier per tile (no
// __syncthreads full-drain). Barrier at end of iter t guarantees (a) all
// waves' tile-(t+1) loads landed, (b) all waves retired ds_reads of buf t
// (consumed by MFMAs pre-barrier) -> overwrite of buf t at iter t+1 is safe.
// Staging: wave w fills k-subtile plane w via width-16 global_load_lds
// (LDS dest wave-uniform + lane*16B; per-lane global source).
// Frag-read layout [4][128][8] conflict-free ds_read_b128.
// ---------------------------------------------------------------------------
__global__ __launch_bounds__(256)
void gemm_final_kernel(const _Float16* __restrict__ A,
                       const _Float16* __restrict__ xh,
                       const _Float16* __restrict__ WT,
                       const float* __restrict__ bias, float* __restrict__ C) {
    __shared__ _Float16 As[2][4][128][8];
    __shared__ _Float16 Bs[2][4][128][8];

    const int t = threadIdx.x;
    const int lane = t & 63;
    const int w = t >> 6;
    const int wr = w >> 1;
    const int wc = w & 1;
    const long m0 = (long)blockIdx.x * 128;
    const int n0 = blockIdx.y * 128;

    const long ar0 = m0 + lane, ar1 = m0 + 64 + lane;
    const _Float16* Aa0 = A + ar0 * ACOLS + w * 8;
    const _Float16* Aa1 = A + ar1 * ACOLS + w * 8;
    const _Float16* Ax0 = xh + ar0 * D + w * 8;
    const _Float16* Ax1 = xh + ar1 * D + w * 8;
    const _Float16* Bg0 = WT + (long)(n0 + lane) * KCAT + w * 8;
    const _Float16* Bg1 = WT + (long)(n0 + 64 + lane) * KCAT + w * 8;

    f32x4 acc[4][4];
#pragma unroll
    for (int i = 0; i < 4; ++i)
#pragma unroll
        for (int j = 0; j < 4; ++j) acc[i][j] = (f32x4){0.f, 0.f, 0.f, 0.f};

    const int kg = lane >> 4;
    const int rr = lane & 15;
    constexpr int NT = KCAT / 32;  // 40

    auto stage = [&](int kt, int buf) {
        const int k0 = kt * 32;
        _Float16* a0 = &As[buf][w][0][0];
        _Float16* a1 = &As[buf][w][64][0];
        _Float16* b0 = &Bs[buf][w][0][0];
        _Float16* b1 = &Bs[buf][w][64][0];
        if (k0 < ACOLS) {
            load_lds16(Aa0 + k0, a0);
            load_lds16(Aa1 + k0, a1);
        } else {
            load_lds16(Ax0 + (k0 - ACOLS), a0);
            load_lds16(Ax1 + (k0 - ACOLS), a1);
        }
        load_lds16(Bg0 + k0, b0);
        load_lds16(Bg1 + k0, b1);
    };

    auto compute = [&](int buf) {
        f16x8 af[4], bf[4];
#pragma unroll
        for (int f = 0; f < 4; ++f) {
            af[f] = *reinterpret_cast<const f16x8*>(
                &As[buf][kg][wr * 64 + f * 16 + rr][0]);
            bf[f] = *reinterpret_cast<const f16x8*>(
                &Bs[buf][kg][wc * 64 + f * 16 + rr][0]);
        }
#pragma unroll
        for (int i = 0; i < 4; ++i)
#pragma unroll
            for (int j = 0; j < 4; ++j)
                acc[i][j] = __builtin_amdgcn_mfma_f32_16x16x32_f16(
                    af[i], bf[j], acc[i][j], 0, 0, 0);
    };

    // prologue: stage tile 0, drain, barrier
    stage(0, 0);
    asm volatile("s_waitcnt vmcnt(0)" ::: "memory");
    __builtin_amdgcn_sched_barrier(0);
    __builtin_amdgcn_s_barrier();
    __builtin_amdgcn_sched_barrier(0);

    int cur = 0;
    for (int kt = 0; kt < NT; ++kt) {
        if (kt + 1 < NT) stage(kt + 1, cur ^ 1);  // issue next tile early
        compute(cur);                             // ds_read + 16 MFMA
        asm volatile("s_waitcnt vmcnt(0)" ::: "memory");  // next tile landed
        __builtin_amdgcn_sched_barrier(0);
        __builtin_amdgcn_s_barrier();             // all waves: landed + reads done
        __builtin_amdgcn_sched_barrier(0);
        cur ^= 1;
    }

    // epilogue: C/D map col=lane&15, row=(lane>>4)*4+reg
    const int crow0 = (lane >> 4) * 4;
    const int ccol = lane & 15;
#pragma unroll
    for (int i = 0; i < 4; ++i) {
        const long row = m0 + wr * 64 + i * 16 + crow0;
#pragma unroll
        for (int j = 0; j < 4; ++j) {
            const int col = n0 + wc * 64 + j * 16 + ccol;
            const float b = bias[col];
#pragma unroll
            for (int q = 0; q < 4; ++q) {
                const long rgl = row + q;
                if (rgl < N) C[rgl * 256 + col] = tanhf(acc[i][j][q] + b);
            }
        }
    }
}

// ---------------------------------------------------------------------------
extern "C" void kernel_launch(void* const* d_in, const int* in_sizes, int n_in,
                              void* d_out, int out_size, void* d_ws, size_t ws_size,
                              hipStream_t stream) {
    const float* x           = (const float*)d_in[0];
    const int*   edges       = (const int*)d_in[1];   // [4][2][400000] int32
    const float* weight      = (const float*)d_in[2]; // [4][256][256]
    const float* loop_weight = (const float*)d_in[3]; // [256][256]
    const float* h_bias      = (const float*)d_in[4]; // [256]
    float*       out         = (float*)d_out;
    (void)in_sizes; (void)n_in; (void)out_size; (void)ws_size;

    size_t off = 0;
    auto carve = [&](size_t bytes) -> void* {
        void* p = (char*)d_ws + off;
        off = (off + bytes + 255) & ~(size_t)255;
        return p;
    };

    _Float16* A     = (_Float16*)carve((size_t)AROWS * ACOLS * sizeof(_Float16));
    _Float16* xh    = (_Float16*)carve((size_t)AROWS * D * sizeof(_Float16));
    _Float16* WT    = (_Float16*)carve((size_t)KCAT * 256 * sizeof(_Float16));
    int*      gcnt  = (int*)carve((size_t)NBKT * sizeof(int));
    int*      ovf_n = (int*)carve(256);
    int2*     ovf   = (int2*)carve((size_t)MAXOVF * sizeof(int2));
    // ws total ~129 MB (proven available). bucket array (8 MB) aliases d_out:
    // dead before gemm_final overwrites it (stream-ordered).
    uint* buckets = (uint*)d_out;  // NBKT*BCAP*4 = 8.03 MB <= 51.2 MB

    hipMemsetAsync(gcnt, 0, (size_t)NBKT * sizeof(int), stream);
    hipMemsetAsync(ovf_n, 0, sizeof(int), stream);

    wt_build_kernel<<<(256 * KCAT + 255) / 256, 256, 0, stream>>>(weight, loop_weight, WT);
    convert_x_kernel<<<(N * (D / 8) + 255) / 256, 256, 0, stream>>>(x, xh);

    // multisplit edges -> dst-range buckets
    partition_kernel<<<dim3(NCHUNKS, R), 256, 0, stream>>>(edges, gcnt, buckets,
                                                           ovf_n, ovf);
    // LDS slot build + gather fused; writes msg planes into A
    bucket_gather_kernel<<<NBKT * 4, 256, 0, stream>>>(buckets, gcnt, xh,
                                                       ovf, ovf_n, A);
    // out = tanh([A | xh] @ Wcat + bias)
    gemm_final_kernel<<<dim3(AROWS / 128, 2), 256, 0, stream>>>(A, xh, WT, h_bias, out);
}